// Round 5
// baseline (126.435 us; speedup 1.0000x reference)
//
#include <hip/hip_runtime.h>

// out[b,p] = sum_{e,f} x[b,i_p,e] * K[f,p,e] * x[b,j_p,f]
//
// Single fused kernel (R5). Per block (pair p, 256-batch tile):
//   - convert K_p fp32 -> bf16 hi/lo B-fragments into LDS (shared by 4 waves)
//   - each wave: A = x[.,j_p,:] fp32 -> hi/lo in-register (truncation split)
//   - 96 MFMA 16x16x32 bf16 (split-3: Ah*Bh + Ah*Bl + Al*Bh), fp32 acc
//   - epilogue: out = rowsum(D .* x[.,i_p,:]) via fp32 VALU + shfl reduce
//
// Truncation split: hi = bf16(top 16 bits of f), lo = bf16_rne(f - hi).
// Product rel err ~2^-17; accumulated abs err ~1e-4 << 0.0625 (R3/R4 passed).
//
// XCD pinning: p = bid % 496; 496 % 8 == 0 so all 8 M-tile blocks of pair p
// land on the same XCD -> K_p is fetched from HBM once, L2-resident after.

constexpr int BATCH  = 2048;
constexpr int FIELDS = 32;
constexpr int EMBED  = 64;
constexpr int PAIRS  = FIELDS * (FIELDS - 1) / 2;  // 496

typedef __attribute__((ext_vector_type(8))) short  short8;   // 8 bf16 = 4 VGPR
typedef __attribute__((ext_vector_type(4))) float  f32x4;

__device__ __forceinline__ unsigned short bf16_rne(float f) {
    unsigned int u = __float_as_uint(f);
    u = u + 0x7fffu + ((u >> 16) & 1u);
    return (unsigned short)(u >> 16);
}

__global__ __launch_bounds__(256) void opn_fused_kernel(
    const float* __restrict__ x,
    const float* __restrict__ kern,
    float* __restrict__ out)
{
    // B fragments: [0:4096) hi, [4096:8192) lo (ushorts). 16 KB total.
    __shared__ unsigned short smem[8192];

    const int tid  = (int)threadIdx.x;
    const int lane = tid & 63;
    const int wave = tid >> 6;
    const int bid  = (int)blockIdx.x;
    const int p    = bid % PAIRS;          // XCD = p % 8 for all 8 mt blocks
    const int mt   = bid / PAIRS;
    const int g    = lane >> 4;
    const int c    = lane & 15;
    const int Mb   = mt * 256 + wave * 64; // this wave's first batch row

    // pair -> (i, j) per jnp.triu_indices(FIELDS, k=1)
    int i = 0, rem = p;
    while (rem >= FIELDS - 1 - i) { rem -= FIELDS - 1 - i; ++i; }
    const int jf = i + 1 + rem;

    // ---- Phase 1a: issue K loads (16 dwords/thread-slot, coalesced 64B segs) ----
    // fragment chunk idx = (ks*4+nc)*64 + ln ; elem jj: f = ks*32+(ln>>4)*8+jj,
    // e = nc*16+(ln&15). Thread handles idx = tid and tid+256.
    float kv[2][8];
    #pragma unroll
    for (int h = 0; h < 2; ++h) {
        const int idx = tid + h * 256;
        const int ks = idx >> 8;
        const int nc = (idx >> 6) & 3;
        const int ln = idx & 63;
        const int f0 = ks * 32 + (ln >> 4) * 8;
        const int e  = nc * 16 + (ln & 15);
        const float* kbase = kern + (size_t)p * EMBED + e;
        #pragma unroll
        for (int jj = 0; jj < 8; ++jj)
            kv[h][jj] = kbase[(size_t)(f0 + jj) * (PAIRS * EMBED)];
    }

    // ---- Phase 1b: issue A loads (16 x float4/lane) ----
    float4 xa[4][2][2];  // [mr][ks][half]
    #pragma unroll
    for (int mr = 0; mr < 4; ++mr) {
        const int row = Mb + mr * 16 + c;
        const float* base = x + ((size_t)row * FIELDS + jf) * EMBED;
        #pragma unroll
        for (int ks = 0; ks < 2; ++ks) {
            xa[mr][ks][0] = *(const float4*)(base + ks * 32 + g * 8);
            xa[mr][ks][1] = *(const float4*)(base + ks * 32 + g * 8 + 4);
        }
    }

    // ---- Phase 2: convert K, stage B-fragments to LDS ----
    #pragma unroll
    for (int h = 0; h < 2; ++h) {
        const int idx = tid + h * 256;
        short8 h8, l8;
        #pragma unroll
        for (int jj = 0; jj < 8; ++jj) {
            const float v = kv[h][jj];
            const unsigned int u = __float_as_uint(v);
            h8[jj] = (short)(u >> 16);                                   // hi = trunc
            l8[jj] = (short)bf16_rne(v - __uint_as_float(u & 0xffff0000u));
        }
        *(short8*)(smem + idx * 8)        = h8;
        *(short8*)(smem + 4096 + idx * 8) = l8;
    }
    __syncthreads();

    // ---- Phase 3: convert A in-register (xa dies here) ----
    short8 ah[4][2], al[4][2];
    #pragma unroll
    for (int mr = 0; mr < 4; ++mr)
        #pragma unroll
        for (int ks = 0; ks < 2; ++ks) {
            const float4 a0 = xa[mr][ks][0], a1 = xa[mr][ks][1];
            const float v[8] = {a0.x, a0.y, a0.z, a0.w, a1.x, a1.y, a1.z, a1.w};
            #pragma unroll
            for (int jj = 0; jj < 8; ++jj) {
                const unsigned int u = __float_as_uint(v[jj]);
                ah[mr][ks][jj] = (short)(u >> 16);
                al[mr][ks][jj] = (short)bf16_rne(v[jj] - __uint_as_float(u & 0xffff0000u));
            }
        }

    // ---- Phase 4: MFMA (per-ks B read from LDS keeps B live regs at 32) ----
    f32x4 acc[4][4];
    #pragma unroll
    for (int mr = 0; mr < 4; ++mr)
        #pragma unroll
        for (int nc = 0; nc < 4; ++nc)
            acc[mr][nc] = (f32x4){0.f, 0.f, 0.f, 0.f};

    #pragma unroll
    for (int ks = 0; ks < 2; ++ks) {
        short8 bh[4], bl[4];
        #pragma unroll
        for (int nc = 0; nc < 4; ++nc) {
            const int off = ((ks * 4 + nc) * 64 + lane) * 8;
            bh[nc] = *(const short8*)(smem + off);
            bl[nc] = *(const short8*)(smem + 4096 + off);
        }
        #pragma unroll
        for (int mr = 0; mr < 4; ++mr)
            #pragma unroll
            for (int nc = 0; nc < 4; ++nc) {
                acc[mr][nc] = __builtin_amdgcn_mfma_f32_16x16x32_bf16(ah[mr][ks], bh[nc], acc[mr][nc], 0, 0, 0);
                acc[mr][nc] = __builtin_amdgcn_mfma_f32_16x16x32_bf16(ah[mr][ks], bl[nc], acc[mr][nc], 0, 0, 0);
                acc[mr][nc] = __builtin_amdgcn_mfma_f32_16x16x32_bf16(al[mr][ks], bh[nc], acc[mr][nc], 0, 0, 0);
            }
    }

    // ---- Epilogue: out[row, p] = sum_e D[row][e] * x[row][i][e] ----
    // D layout (m89, validated R3/R4): reg t of acc[mr][nc] = D[Mb+mr*16+4g+t][nc*16+c]
    float z[4][4];
    #pragma unroll
    for (int mr = 0; mr < 4; ++mr)
        #pragma unroll
        for (int t = 0; t < 4; ++t)
            z[mr][t] = 0.f;

    const size_t xi_base = (size_t)i * EMBED + c;
    #pragma unroll
    for (int mr = 0; mr < 4; ++mr)
        #pragma unroll
        for (int t = 0; t < 4; ++t) {
            const int row = Mb + mr * 16 + 4 * g + t;
            const float* xi = x + (size_t)row * (FIELDS * EMBED) + xi_base;
            #pragma unroll
            for (int nc = 0; nc < 4; ++nc)
                z[mr][t] = fmaf(acc[mr][nc][t], xi[nc * 16], z[mr][t]);
        }

    #pragma unroll
    for (int mask = 1; mask < 16; mask <<= 1)
        #pragma unroll
        for (int mr = 0; mr < 4; ++mr)
            #pragma unroll
            for (int t = 0; t < 4; ++t)
                z[mr][t] += __shfl_xor(z[mr][t], mask, 64);

    if (c < 4) {  // lane c==t writes rows {Mb + mr*16 + 4g + t}
        const int t = c;
        #pragma unroll
        for (int mr = 0; mr < 4; ++mr) {
            const int row = Mb + mr * 16 + 4 * g + t;
            out[(size_t)row * PAIRS + p] = z[mr][t];
        }
    }
}

extern "C" void kernel_launch(void* const* d_in, const int* in_sizes, int n_in,
                              void* d_out, int out_size, void* d_ws, size_t ws_size,
                              hipStream_t stream) {
    const float* x    = (const float*)d_in[0];
    const float* kern = (const float*)d_in[1];
    float*       out  = (float*)d_out;

    opn_fused_kernel<<<dim3(PAIRS * 8), dim3(256), 0, stream>>>(x, kern, out);
}